// Round 5
// baseline (192.324 us; speedup 1.0000x reference)
//
#include <hip/hip_runtime.h>

#define SEQ 2048
#define HD 64
#define NBH 24

// ---------------- workspace layout (proven rounds 5-8; K/VT chunk-XOR-swizzled since r11) ----------------
#define MB_OFF   0
#define MB_BYTES (32 * 32 * 512)                 // 512 KB: [qtb][kt][64 q-rows][u64 of k-bits]
#define QB_OFF   (MB_OFF + MB_BYTES)
#define QK_BYTES (NBH * SEQ * HD * 2)            // 6 MB bf16, plain 128B rows
#define KB_OFF   (QB_OFF + QK_BYTES)
#define VT_OFF   (KB_OFF + QK_BYTES)             // V^T pre-tiled: [bh][kt] 8KB tiles, d-major 128B rows
#define WS_NEED  ((size_t)(VT_OFF + QK_BYTES))   // ~18.5 MB

typedef __bf16 bfrag8 __attribute__((ext_vector_type(8)));
typedef __bf16 bf16x4 __attribute__((ext_vector_type(4)));
typedef float  floatx4 __attribute__((ext_vector_type(4)));
typedef float  floatx16 __attribute__((ext_vector_type(16)));

__device__ __forceinline__ floatx4 mfma_16x16x32(bfrag8 a, bfrag8 b, floatx4 c) {
    return __builtin_amdgcn_mfma_f32_16x16x32_bf16(a, b, c, 0, 0, 0);
}
__device__ __forceinline__ floatx16 mfma_32x32x16(bfrag8 a, bfrag8 b, floatx16 c) {
    return __builtin_amdgcn_mfma_f32_32x32x16_bf16(a, b, c, 0, 0, 0);
}
__device__ __forceinline__ void gld16(const unsigned char* g, unsigned char* l) {
    __builtin_amdgcn_global_load_lds(
        (const __attribute__((address_space(1))) unsigned int*)g,
        (__attribute__((address_space(3))) unsigned int*)l, 16, 0, 0);
}

// ================= prepass (rounds 5-8 + chunk-XOR swizzle on K and V^T rows — proven r11) =================
__global__ __launch_bounds__(256)
void prep_kernel(const float* __restrict__ qp, const float* __restrict__ kp,
                 const float* __restrict__ vp, const int* __restrict__ maskp,
                 unsigned char* __restrict__ ws)
{
    __shared__ __attribute__((aligned(16))) unsigned char parena[64 * 68 * 4];
    const int t = threadIdx.x;
    const int b = blockIdx.x;

    if (b < 1536) {
        int gt  = b * 256 + t;
        int row = gt >> 3;
        int c   = gt & 7;
        const floatx4* qs = (const floatx4*)(qp + row * 64 + c * 8);
        const floatx4* ks = (const floatx4*)(kp + row * 64 + c * 8);
        floatx4 q0 = qs[0], q1 = qs[1];
        floatx4 k0 = ks[0], k1 = ks[1];
        bfrag8 qpk, kpk;
        #pragma unroll
        for (int i = 0; i < 4; ++i) {
            qpk[i] = (__bf16)q0[i]; qpk[4 + i] = (__bf16)q1[i];
            kpk[i] = (__bf16)k0[i]; kpk[4 + i] = (__bf16)k1[i];
        }
        *(bfrag8*)(ws + QB_OFF + row * 128 + c * 16) = qpk;                       // Q linear (read once)
        *(bfrag8*)(ws + KB_OFF + row * 128 + ((c ^ (row & 7)) * 16)) = kpk;       // K swizzled
    } else if (b < 2304) {
        int bb = b - 1536, bh = bb >> 5, kt = bb & 31;
        float* lf = (float*)parena;                 // [64 k][68 d]
        const floatx4* vg = (const floatx4*)(vp + (bh * SEQ + kt * 64) * 64);
        #pragma unroll
        for (int it = 0; it < 4; ++it) {
            int f = t + it * 256;
            int r = f >> 4, c4 = f & 15;
            floatx4 val = vg[f];
            #pragma unroll
            for (int i = 0; i < 4; ++i) lf[r * 68 + c4 * 4 + i] = val[i];
        }
        __syncthreads();
        int d = t >> 2, kseg = t & 3;
        unsigned char* tb = ws + VT_OFF + (size_t)(bh * 32 + kt) * 8192 + d * 128;
        #pragma unroll
        for (int jj = 0; jj < 2; ++jj) {
            bfrag8 pk;
            #pragma unroll
            for (int e = 0; e < 8; ++e)
                pk[e] = (__bf16)lf[(kseg * 16 + jj * 8 + e) * 68 + d];
            *(bfrag8*)(tb + (((kseg * 2 + jj) ^ (d & 7)) * 16)) = pk;             // V^T swizzled
        }
    } else {
        int cc = b - 2304, qtb = cc >> 5, kt = cc & 31;
        const int w = t >> 6, lane = t & 63;
        #pragma unroll
        for (int it = 0; it < 16; ++it) {
            int rr = it * 4 + w;
            unsigned long long bl = __ballot(maskp[(qtb * 64 + rr) * SEQ + kt * 64 + lane] != 0);
            if (lane == 0)
                *(unsigned long long*)(ws + MB_OFF + (size_t)((qtb * 32 + kt) * 64 + rr) * 8) = bl;
        }
    }
}

// ======== main (round 13): q=128/block, slot-sharing wave pairs.
//          8 waves = 2 q-subs x 4 kt-classes; pair (sub0,sub1) shares one 16KB K/V slot
//          (sub0 DMAs K, sub1 DMAs V); per-wave math = proven round-11 verbatim.
//          Staged volume halves (196MB); 2 barriers/iter; 2 blocks/CU for overlap. ========
__global__ __launch_bounds__(512, 4)
void normattn_main(const unsigned char* __restrict__ ws,
                   const float* __restrict__ gammap, const float* __restrict__ betap,
                   float* __restrict__ outp)
{
    __shared__ __attribute__((aligned(16))) unsigned char sm[65536];   // 4 x 16KB shared slots

    const int tid  = threadIdx.x;
    const int w    = tid >> 6;          // 0..7
    const int sub  = w >> 2;            // q sub-tile (0: rows 0-63, 1: rows 64-127)
    const int wq   = w & 3;             // kt class
    const int lane = tid & 63;
    const int l32  = lane & 31;
    const int hi   = lane >> 5;
    const int bx   = blockIdx.x;        // 128-row q tile
    const int bh   = blockIdx.y;
    const int qbase = bx * 128 + sub * 64;     // this wave's 64-row q block

    unsigned char* slotK = sm + wq * 16384;
    unsigned char* slotV = slotK + 8192;

    const unsigned char* gKt = ws + KB_OFF + (size_t)(bh * SEQ) * 128;      // + kt*8192
    const unsigned char* gVt = ws + VT_OFF + (size_t)(bh * 32) * 8192;      // + kt*8192
    const unsigned char* gMb = ws + MB_OFF + (size_t)((bx * 2 + sub) * 32) * 512;   // + kt*512

    // Q fragments, both q-halves (B-operand, 32x32x16): lane holds col q = qbase + qh*32 + l32
    bfrag8 qb[2][4];
    #pragma unroll
    for (int qh = 0; qh < 2; ++qh)
        #pragma unroll
        for (int dstep = 0; dstep < 4; ++dstep)
            qb[qh][dstep] = *(const bfrag8*)(ws + QB_OFF +
                (size_t)(bh * SEQ + qbase + qh * 32 + l32) * 128 + dstep * 32 + hi * 16);

    // acc[qh][dh]: O^T[d = dh*32 + (r&3)+4*hi+8*(r>>2)][q = qbase + qh*32 + l32], partial over kt ≡ wq (4)
    floatx16 acc[2][2];
    #pragma unroll
    for (int i = 0; i < 4; ++i) acc[i >> 1][i & 1] = (floatx16)0.0f;

    auto stage = [&](int kt) {          // pair-split DMA: sub0 -> K half, sub1 -> V half
        if (sub == 0) {
            const unsigned char* gk = gKt + (size_t)kt * 8192 + lane * 16;
            #pragma unroll
            for (int c = 0; c < 8; ++c) gld16(gk + c * 1024, slotK + c * 1024);
        } else {
            const unsigned char* gv = gVt + (size_t)kt * 8192 + lane * 16;
            #pragma unroll
            for (int c = 0; c < 8; ++c) gld16(gv + c * 1024, slotV + c * 1024);
        }
    };
    unsigned long long mnx0, mnx1;
    auto loadmask = [&](int kt) {
        mnx0 = *(const unsigned long long*)(gMb + (size_t)kt * 512 + l32 * 8);
        mnx1 = *(const unsigned long long*)(gMb + (size_t)kt * 512 + 256 + l32 * 8);
    };

    // prologue: stage tile wq, wait own half, rendezvous
    stage(wq);
    loadmask(wq);
    asm volatile("s_waitcnt vmcnt(0)" ::: "memory");
    __builtin_amdgcn_s_barrier();                        // both halves of every slot present

    for (int i = 0; i < 8; ++i) {
        const int kt = wq + 4 * i;

        // ---- B: all 16 fragment reads of tile kt
        bfrag8 ka[2][4], va[2][2][2];
        #pragma unroll
        for (int kh = 0; kh < 2; ++kh)
            #pragma unroll
            for (int d = 0; d < 4; ++d)
                ka[kh][d] = *(const bfrag8*)(slotK + (kh * 32 + l32) * 128 +
                                             (((d * 2 + hi) ^ (l32 & 7)) << 4));
        #pragma unroll
        for (int dh = 0; dh < 2; ++dh)
            #pragma unroll
            for (int kh = 0; kh < 2; ++kh)
                #pragma unroll
                for (int ks = 0; ks < 2; ++ks)
                    va[dh][kh][ks] = *(const bfrag8*)(slotV + (dh * 32 + l32) * 128 +
                                                      (((kh * 4 + ks * 2 + hi) ^ (l32 & 7)) << 4));
        asm volatile("s_waitcnt lgkmcnt(0)" ::: "memory");
        __builtin_amdgcn_s_barrier();                    // C: all waves' reads done -> slots free

        const unsigned long long mr0 = mnx0, mr1 = mnx1; // snapshot before prefetch clobbers
        if (i < 7) { stage(kt + 4); loadmask(kt + 4); }  // D: DMA hides under compute below

        // ---- E: compute (proven round-11 math, verbatim)
        #pragma unroll
        for (int kh = 0; kh < 2; ++kh) {
            floatx16 st0 = (floatx16)0.0f, st1 = (floatx16)0.0f;
            #pragma unroll
            for (int d = 0; d < 4; ++d) {
                st0 = mfma_32x32x16(ka[kh][d], qb[0][d], st0);
                st1 = mfma_32x32x16(ka[kh][d], qb[1][d], st1);
            }
            #pragma unroll
            for (int qh = 0; qh < 2; ++qh) {
                const floatx16 st = qh ? st1 : st0;
                const unsigned long long mrow = qh ? mr1 : mr0;
                const unsigned bits = (unsigned)(mrow >> (kh * 32 + 4 * hi));
                unsigned u[8];
                #pragma unroll
                for (int j = 0; j < 8; ++j) {
                    const int kl0 = 2 * (j & 1) + 8 * (j >> 1);
                    float a = ((bits >> kl0) & 1u) ? st[2 * j] : -10000.0f;
                    float b = ((bits >> (kl0 + 1)) & 1u) ? st[2 * j + 1] : -10000.0f;
                    asm("v_cvt_pk_bf16_f32 %0, %1, %2" : "=v"(u[j]) : "v"(a), "v"(b));
                }
                asm("v_permlane32_swap_b32 %0, %1" : "+v"(u[0]), "+v"(u[2]));
                asm("v_permlane32_swap_b32 %0, %1" : "+v"(u[1]), "+v"(u[3]));
                asm("v_permlane32_swap_b32 %0, %1" : "+v"(u[4]), "+v"(u[6]));
                asm("v_permlane32_swap_b32 %0, %1" : "+v"(u[5]), "+v"(u[7]));
                union { unsigned int w4[4]; bfrag8 f; } c0, c1;
                c0.w4[0] = u[0]; c0.w4[1] = u[1]; c0.w4[2] = u[2]; c0.w4[3] = u[3];
                c1.w4[0] = u[4]; c1.w4[1] = u[5]; c1.w4[2] = u[6]; c1.w4[3] = u[7];

                acc[qh][0] = mfma_32x32x16(va[0][kh][0], c0.f, acc[qh][0]);
                acc[qh][0] = mfma_32x32x16(va[0][kh][1], c1.f, acc[qh][0]);
                acc[qh][1] = mfma_32x32x16(va[1][kh][0], c0.f, acc[qh][1]);
                acc[qh][1] = mfma_32x32x16(va[1][kh][1], c1.f, acc[qh][1]);
            }
        }

        // ---- F/G: own DMA half arrived; rendezvous -> slot kt+4 fully present
        asm volatile("s_waitcnt vmcnt(0)" ::: "memory");
        __builtin_amdgcn_s_barrier();
    }

    // ---- epilogue: tree-reduce the 4 kt-class partials per sub, then LN ----
    auto dump = [&](int region) {
        unsigned char* base = sm + region * 16384;
        #pragma unroll
        for (int qh = 0; qh < 2; ++qh)
            #pragma unroll
            for (int dh = 0; dh < 2; ++dh)
                #pragma unroll
                for (int jj = 0; jj < 4; ++jj) {
                    floatx4 t;
                    #pragma unroll
                    for (int e = 0; e < 4; ++e) t[e] = acc[qh][dh][jj * 4 + e];
                    *(floatx4*)(base + (qh * 2 + dh) * 4096 + jj * 1024 + lane * 16) = t;
                }
    };
    auto addin = [&](int region) {
        const unsigned char* base = sm + region * 16384;
        #pragma unroll
        for (int qh = 0; qh < 2; ++qh)
            #pragma unroll
            for (int dh = 0; dh < 2; ++dh)
                #pragma unroll
                for (int jj = 0; jj < 4; ++jj) {
                    floatx4 t = *(const floatx4*)(base + (qh * 2 + dh) * 4096 + jj * 1024 + lane * 16);
                    #pragma unroll
                    for (int e = 0; e < 4; ++e) acc[qh][dh][jj * 4 + e] += t[e];
                }
    };

    if (wq >= 2) dump(sub * 2 + (wq - 2));
    __syncthreads();
    if (wq <= 1) addin(sub * 2 + wq);        // wq0 += wq2 ; wq1 += wq3
    if (wq == 1) dump(sub * 2 + 1);          // in-wave read-then-write, dep-ordered
    __syncthreads();
    if (wq == 0) {
        addin(sub * 2 + 1);                  // += (wq1+wq3)  -> full sum
        float s = 0.0f, s2 = 0.0f;
        #pragma unroll
        for (int qh = 0; qh < 2; ++qh) {}    // (acc indexed below; sums per q-row are per qh)
        #pragma unroll
        for (int qh = 0; qh < 2; ++qh) {
            float ss = 0.0f, ss2 = 0.0f;
            #pragma unroll
            for (int dh = 0; dh < 2; ++dh)
                #pragma unroll
                for (int r = 0; r < 16; ++r) { float x = acc[qh][dh][r]; ss += x; ss2 += x * x; }
            ss  += __shfl_xor(ss, 32);       // partner lane holds complementary d set
            ss2 += __shfl_xor(ss2, 32);
            float mean = ss * (1.0f / 64.0f);
            float var  = ss2 * (1.0f / 64.0f) - mean * mean;
            float rstd = rsqrtf(var + 1e-12f);
            float* orow = outp + (size_t)(bh * SEQ + qbase + qh * 32 + l32) * 64;
            #pragma unroll
            for (int dh = 0; dh < 2; ++dh)
                #pragma unroll
                for (int jj = 0; jj < 4; ++jj) {
                    const int d0 = dh * 32 + jj * 8 + 4 * hi;
                    floatx4 gg = *(const floatx4*)(gammap + d0);
                    floatx4 bb = *(const floatx4*)(betap + d0);
                    floatx4 o;
                    #pragma unroll
                    for (int e = 0; e < 4; ++e)
                        o[e] = (acc[qh][dh][jj * 4 + e] - mean) * rstd * gg[e] + bb[e];
                    *(floatx4*)(orow + d0) = o;
                }
        }
        (void)s; (void)s2;
    }
}

// ================= fallback (round-2 kernel — proven) =================
#define KROW 72
#define SROW 40
__global__ __launch_bounds__(256, 4)
void normattn_fallback(const float* __restrict__ qp, const float* __restrict__ kp,
                       const float* __restrict__ vp, const int* __restrict__ maskp,
                       const float* __restrict__ gammap, const float* __restrict__ betap,
                       float* __restrict__ outp)
{
    __shared__ __attribute__((aligned(16))) __bf16 sQ[64 * KROW];
    __shared__ __attribute__((aligned(16))) __bf16 sK[64 * KROW];
    __shared__ __attribute__((aligned(16))) __bf16 sV[64 * KROW];
    __shared__ __attribute__((aligned(16))) __bf16 sS[4][16 * SROW];
    __shared__ __attribute__((aligned(8)))  unsigned int sMw[64][2];

    const int tid = threadIdx.x, wave = tid >> 6, lane = tid & 63;
    const int quad = lane >> 4, l16 = lane & 15;
    const int q0 = blockIdx.x * 64, bh = blockIdx.y;
    const int base = bh * SEQ * HD;
    {
        const floatx4* qg = (const floatx4*)(qp + base + q0 * HD);
        #pragma unroll
        for (int it = 0; it < 4; ++it) {
            int idx = tid + it * 256, r = idx >> 4, c = idx & 15;
            floatx4 val = qg[idx];
            bf16x4 pk = {(__bf16)val[0], (__bf16)val[1], (__bf16)val[2], (__bf16)val[3]};
            *(bf16x4*)&sQ[r * KROW + c * 4] = pk;
        }
    }
    __syncthreads();
    bfrag8 qa0 = *(const bfrag8*)&sQ[(wave * 16 + l16) * KROW + quad * 8];
    bfrag8 qa1 = *(const bfrag8*)&sQ[(wave * 16 + l16) * KROW + quad * 8 + 32];
    floatx4 acc[4];
    #pragma unroll
    for (int i = 0; i < 4; ++i) acc[i] = (floatx4)0.0f;
    const int qrow_loc = wave * 16 + quad * 4;
    const int qrb = q0 + qrow_loc;
    for (int kb = 0; kb < SEQ; kb += 64) {
        __syncthreads();
        {
            const floatx4* kg = (const floatx4*)(kp + base + kb * HD);
            #pragma unroll
            for (int it = 0; it < 4; ++it) {
                int idx = tid + it * 256, r = idx >> 4, c = idx & 15;
                floatx4 val = kg[idx];
                bf16x4 pk = {(__bf16)val[0], (__bf16)val[1], (__bf16)val[2], (__bf16)val[3]};
                *(bf16x4*)&sK[r * KROW + c * 4] = pk;
            }
        }
        {
            int d = tid & 63;
            #pragma unroll
            for (int it = 0; it < 4; ++it) {
                int k4 = (tid >> 6) + it * 4;
                bf16x4 pk;
                #pragma unroll
                for (int i = 0; i < 4; ++i) pk[i] = (__bf16)vp[base + (kb + k4 * 4 + i) * HD + d];
                *(bf16x4*)&sV[d * KROW + k4 * 4] = pk;
            }
        }
        #pragma unroll
        for (int it = 0; it < 16; ++it) {
            int rr = it * 4 + wave;
            unsigned long long bl = __ballot(maskp[(q0 + rr) * SEQ + kb + lane] != 0);
            if (lane == 0) { sMw[rr][0] = (unsigned)bl; sMw[rr][1] = (unsigned)(bl >> 32); }
        }
        __syncthreads();
        unsigned long long mrow[4];
        #pragma unroll
        for (int r = 0; r < 4; ++r) mrow[r] = *(const unsigned long long*)&sMw[qrow_loc + r][0];
        #pragma unroll
        for (int kc = 0; kc < 64; kc += 32) {
            floatx4 s0 = (floatx4)0.0f, s1 = (floatx4)0.0f;
            bfrag8 b00 = *(const bfrag8*)&sK[(kc + l16) * KROW + quad * 8];
            bfrag8 b01 = *(const bfrag8*)&sK[(kc + l16) * KROW + quad * 8 + 32];
            bfrag8 b10 = *(const bfrag8*)&sK[(kc + 16 + l16) * KROW + quad * 8];
            bfrag8 b11 = *(const bfrag8*)&sK[(kc + 16 + l16) * KROW + quad * 8 + 32];
            s0 = mfma_16x16x32(qa0, b00, s0);
            s0 = mfma_16x16x32(qa1, b01, s0);
            s1 = mfma_16x16x32(qa0, b10, s1);
            s1 = mfma_16x16x32(qa1, b11, s1);
            #pragma unroll
            for (int r = 0; r < 4; ++r) {
                float v0 = ((mrow[r] >> (kc + l16)) & 1ull) ? s0[r] : -10000.0f;
                float v1 = ((mrow[r] >> (kc + 16 + l16)) & 1ull) ? s1[r] : -10000.0f;
                sS[wave][(quad * 4 + r) * SROW + l16] = (__bf16)v0;
                sS[wave][(quad * 4 + r) * SROW + 16 + l16] = (__bf16)v1;
            }
            asm volatile("s_waitcnt lgkmcnt(0)" ::: "memory");
            bfrag8 pa = *(const bfrag8*)&sS[wave][l16 * SROW + quad * 8];
            #pragma unroll
            for (int nt = 0; nt < 4; ++nt) {
                bfrag8 vb = *(const bfrag8*)&sV[(nt * 16 + l16) * KROW + kc + quad * 8];
                acc[nt] = mfma_16x16x32(pa, vb, acc[nt]);
            }
        }
    }
    float g[4], bt[4];
    #pragma unroll
    for (int nt = 0; nt < 4; ++nt) { g[nt] = gammap[nt * 16 + l16]; bt[nt] = betap[nt * 16 + l16]; }
    #pragma unroll
    for (int r = 0; r < 4; ++r) {
        float s = 0.0f, s2 = 0.0f;
        #pragma unroll
        for (int nt = 0; nt < 4; ++nt) { float xx = acc[nt][r]; s += xx; s2 += xx * xx; }
        #pragma unroll
        for (int off = 1; off < 16; off <<= 1) { s += __shfl_xor(s, off); s2 += __shfl_xor(s2, off); }
        float mean = s * (1.0f / 64.0f);
        float var = s2 * (1.0f / 64.0f) - mean * mean;
        float rstd = rsqrtf(var + 1e-12f);
        float* orow = outp + base + (qrb + r) * HD;
        #pragma unroll
        for (int nt = 0; nt < 4; ++nt)
            orow[nt * 16 + l16] = (acc[nt][r] - mean) * rstd * g[nt] + bt[nt];
    }
}

extern "C" void kernel_launch(void* const* d_in, const int* in_sizes, int n_in,
                              void* d_out, int out_size, void* d_ws, size_t ws_size,
                              hipStream_t stream) {
    const float* q     = (const float*)d_in[0];
    const float* k     = (const float*)d_in[1];
    const float* v     = (const float*)d_in[2];
    const int*   mask  = (const int*)d_in[3];
    const float* gamma = (const float*)d_in[4];
    const float* beta  = (const float*)d_in[5];
    float* out = (float*)d_out;

    if (ws_size >= WS_NEED) {
        unsigned char* ws = (unsigned char*)d_ws;
        prep_kernel<<<3328, 256, 0, stream>>>(q, k, v, mask, ws);
        dim3 grid(16, NBH);
        normattn_main<<<grid, 512, 0, stream>>>(ws, gamma, beta, out);
    } else {
        dim3 grid(32, NBH);
        normattn_fallback<<<grid, 256, 0, stream>>>(q, k, v, mask, gamma, beta, out);
    }
}

// Round 6
// 154.621 us; speedup vs baseline: 1.2438x; 1.2438x over previous
//
#include <hip/hip_runtime.h>

#define SEQ 2048
#define HD 64
#define NBH 24

// ---------------- workspace layout (proven rounds 5-8; K/VT chunk-XOR-swizzled since r11) ----------------
#define MB_OFF   0
#define MB_BYTES (32 * 32 * 512)                 // 512 KB: [qtb][kt][64 q-rows][u64 of k-bits]
#define QB_OFF   (MB_OFF + MB_BYTES)
#define QK_BYTES (NBH * SEQ * HD * 2)            // 6 MB bf16, plain 128B rows
#define KB_OFF   (QB_OFF + QK_BYTES)
#define VT_OFF   (KB_OFF + QK_BYTES)             // V^T pre-tiled: [bh][kt] 8KB tiles, d-major 128B rows
#define WS_NEED  ((size_t)(VT_OFF + QK_BYTES))   // ~18.5 MB

typedef __bf16 bfrag8 __attribute__((ext_vector_type(8)));
typedef __bf16 bf16x4 __attribute__((ext_vector_type(4)));
typedef float  floatx4 __attribute__((ext_vector_type(4)));
typedef float  floatx16 __attribute__((ext_vector_type(16)));

__device__ __forceinline__ floatx4 mfma_16x16x32(bfrag8 a, bfrag8 b, floatx4 c) {
    return __builtin_amdgcn_mfma_f32_16x16x32_bf16(a, b, c, 0, 0, 0);
}
__device__ __forceinline__ floatx16 mfma_32x32x16(bfrag8 a, bfrag8 b, floatx16 c) {
    return __builtin_amdgcn_mfma_f32_32x32x16_bf16(a, b, c, 0, 0, 0);
}
__device__ __forceinline__ void gld16(const unsigned char* g, unsigned char* l) {
    __builtin_amdgcn_global_load_lds(
        (const __attribute__((address_space(1))) unsigned int*)g,
        (__attribute__((address_space(3))) unsigned int*)l, 16, 0, 0);
}

// ================= prepass (rounds 5-8 + chunk-XOR swizzle on K and V^T rows — proven r11) =================
__global__ __launch_bounds__(256)
void prep_kernel(const float* __restrict__ qp, const float* __restrict__ kp,
                 const float* __restrict__ vp, const int* __restrict__ maskp,
                 unsigned char* __restrict__ ws)
{
    __shared__ __attribute__((aligned(16))) unsigned char parena[64 * 68 * 4];
    const int t = threadIdx.x;
    const int b = blockIdx.x;

    if (b < 1536) {
        int gt  = b * 256 + t;
        int row = gt >> 3;
        int c   = gt & 7;
        const floatx4* qs = (const floatx4*)(qp + row * 64 + c * 8);
        const floatx4* ks = (const floatx4*)(kp + row * 64 + c * 8);
        floatx4 q0 = qs[0], q1 = qs[1];
        floatx4 k0 = ks[0], k1 = ks[1];
        bfrag8 qpk, kpk;
        #pragma unroll
        for (int i = 0; i < 4; ++i) {
            qpk[i] = (__bf16)q0[i]; qpk[4 + i] = (__bf16)q1[i];
            kpk[i] = (__bf16)k0[i]; kpk[4 + i] = (__bf16)k1[i];
        }
        *(bfrag8*)(ws + QB_OFF + row * 128 + c * 16) = qpk;                       // Q linear (read once)
        *(bfrag8*)(ws + KB_OFF + row * 128 + ((c ^ (row & 7)) * 16)) = kpk;       // K swizzled
    } else if (b < 2304) {
        int bb = b - 1536, bh = bb >> 5, kt = bb & 31;
        float* lf = (float*)parena;                 // [64 k][68 d]
        const floatx4* vg = (const floatx4*)(vp + (bh * SEQ + kt * 64) * 64);
        #pragma unroll
        for (int it = 0; it < 4; ++it) {
            int f = t + it * 256;
            int r = f >> 4, c4 = f & 15;
            floatx4 val = vg[f];
            #pragma unroll
            for (int i = 0; i < 4; ++i) lf[r * 68 + c4 * 4 + i] = val[i];
        }
        __syncthreads();
        int d = t >> 2, kseg = t & 3;
        unsigned char* tb = ws + VT_OFF + (size_t)(bh * 32 + kt) * 8192 + d * 128;
        #pragma unroll
        for (int jj = 0; jj < 2; ++jj) {
            bfrag8 pk;
            #pragma unroll
            for (int e = 0; e < 8; ++e)
                pk[e] = (__bf16)lf[(kseg * 16 + jj * 8 + e) * 68 + d];
            *(bfrag8*)(tb + (((kseg * 2 + jj) ^ (d & 7)) * 16)) = pk;             // V^T swizzled
        }
    } else {
        int cc = b - 2304, qtb = cc >> 5, kt = cc & 31;
        const int w = t >> 6, lane = t & 63;
        #pragma unroll
        for (int it = 0; it < 16; ++it) {
            int rr = it * 4 + w;
            unsigned long long bl = __ballot(maskp[(qtb * 64 + rr) * SEQ + kt * 64 + lane] != 0);
            if (lane == 0)
                *(unsigned long long*)(ws + MB_OFF + (size_t)((qtb * 32 + kt) * 64 + rr) * 8) = bl;
        }
    }
}

// ======== main (round 14): round-13 structure verbatim, launch_bounds (512,4) -> (512,2).
//          (512,4) capped VGPR at 128 -> allocator spilled acc to scratch (r5: VGPR=64,
//          WRITE 54MB, FETCH 130MB). Round-4 precedent: same math under (512,2) = 128 VGPR,
//          zero spill. 64KB LDS + 128 VGPR -> 2 blocks/CU + halved staged volume. ========
__global__ __launch_bounds__(512, 2)
void normattn_main(const unsigned char* __restrict__ ws,
                   const float* __restrict__ gammap, const float* __restrict__ betap,
                   float* __restrict__ outp)
{
    __shared__ __attribute__((aligned(16))) unsigned char sm[65536];   // 4 x 16KB shared slots

    const int tid  = threadIdx.x;
    const int w    = tid >> 6;          // 0..7
    const int sub  = w >> 2;            // q sub-tile (0: rows 0-63, 1: rows 64-127)
    const int wq   = w & 3;             // kt class
    const int lane = tid & 63;
    const int l32  = lane & 31;
    const int hi   = lane >> 5;
    const int bx   = blockIdx.x;        // 128-row q tile
    const int bh   = blockIdx.y;
    const int qbase = bx * 128 + sub * 64;     // this wave's 64-row q block

    unsigned char* slotK = sm + wq * 16384;
    unsigned char* slotV = slotK + 8192;

    const unsigned char* gKt = ws + KB_OFF + (size_t)(bh * SEQ) * 128;      // + kt*8192
    const unsigned char* gVt = ws + VT_OFF + (size_t)(bh * 32) * 8192;      // + kt*8192
    const unsigned char* gMb = ws + MB_OFF + (size_t)((bx * 2 + sub) * 32) * 512;   // + kt*512

    // Q fragments, both q-halves (B-operand, 32x32x16): lane holds col q = qbase + qh*32 + l32
    bfrag8 qb[2][4];
    #pragma unroll
    for (int qh = 0; qh < 2; ++qh)
        #pragma unroll
        for (int dstep = 0; dstep < 4; ++dstep)
            qb[qh][dstep] = *(const bfrag8*)(ws + QB_OFF +
                (size_t)(bh * SEQ + qbase + qh * 32 + l32) * 128 + dstep * 32 + hi * 16);

    // acc[qh][dh]: O^T[d = dh*32 + (r&3)+4*hi+8*(r>>2)][q = qbase + qh*32 + l32], partial over kt ≡ wq (4)
    floatx16 acc[2][2];
    #pragma unroll
    for (int i = 0; i < 4; ++i) acc[i >> 1][i & 1] = (floatx16)0.0f;

    auto stage = [&](int kt) {          // pair-split DMA: sub0 -> K half, sub1 -> V half
        if (sub == 0) {
            const unsigned char* gk = gKt + (size_t)kt * 8192 + lane * 16;
            #pragma unroll
            for (int c = 0; c < 8; ++c) gld16(gk + c * 1024, slotK + c * 1024);
        } else {
            const unsigned char* gv = gVt + (size_t)kt * 8192 + lane * 16;
            #pragma unroll
            for (int c = 0; c < 8; ++c) gld16(gv + c * 1024, slotV + c * 1024);
        }
    };
    unsigned long long mnx0, mnx1;
    auto loadmask = [&](int kt) {
        mnx0 = *(const unsigned long long*)(gMb + (size_t)kt * 512 + l32 * 8);
        mnx1 = *(const unsigned long long*)(gMb + (size_t)kt * 512 + 256 + l32 * 8);
    };

    // prologue: stage tile wq, wait own half, rendezvous
    stage(wq);
    loadmask(wq);
    asm volatile("s_waitcnt vmcnt(0)" ::: "memory");
    __builtin_amdgcn_s_barrier();                        // both halves of every slot present

    for (int i = 0; i < 8; ++i) {
        const int kt = wq + 4 * i;

        // ---- B: all 16 fragment reads of tile kt
        bfrag8 ka[2][4], va[2][2][2];
        #pragma unroll
        for (int kh = 0; kh < 2; ++kh)
            #pragma unroll
            for (int d = 0; d < 4; ++d)
                ka[kh][d] = *(const bfrag8*)(slotK + (kh * 32 + l32) * 128 +
                                             (((d * 2 + hi) ^ (l32 & 7)) << 4));
        #pragma unroll
        for (int dh = 0; dh < 2; ++dh)
            #pragma unroll
            for (int kh = 0; kh < 2; ++kh)
                #pragma unroll
                for (int ks = 0; ks < 2; ++ks)
                    va[dh][kh][ks] = *(const bfrag8*)(slotV + (dh * 32 + l32) * 128 +
                                                      (((kh * 4 + ks * 2 + hi) ^ (l32 & 7)) << 4));
        asm volatile("s_waitcnt lgkmcnt(0)" ::: "memory");
        __builtin_amdgcn_s_barrier();                    // C: all waves' reads done -> slots free

        const unsigned long long mr0 = mnx0, mr1 = mnx1; // snapshot before prefetch clobbers
        if (i < 7) { stage(kt + 4); loadmask(kt + 4); }  // D: DMA hides under compute below

        // ---- E: compute (proven round-11 math, verbatim)
        #pragma unroll
        for (int kh = 0; kh < 2; ++kh) {
            floatx16 st0 = (floatx16)0.0f, st1 = (floatx16)0.0f;
            #pragma unroll
            for (int d = 0; d < 4; ++d) {
                st0 = mfma_32x32x16(ka[kh][d], qb[0][d], st0);
                st1 = mfma_32x32x16(ka[kh][d], qb[1][d], st1);
            }
            #pragma unroll
            for (int qh = 0; qh < 2; ++qh) {
                const floatx16 st = qh ? st1 : st0;
                const unsigned long long mrow = qh ? mr1 : mr0;
                const unsigned bits = (unsigned)(mrow >> (kh * 32 + 4 * hi));
                unsigned u[8];
                #pragma unroll
                for (int j = 0; j < 8; ++j) {
                    const int kl0 = 2 * (j & 1) + 8 * (j >> 1);
                    float a = ((bits >> kl0) & 1u) ? st[2 * j] : -10000.0f;
                    float b = ((bits >> (kl0 + 1)) & 1u) ? st[2 * j + 1] : -10000.0f;
                    asm("v_cvt_pk_bf16_f32 %0, %1, %2" : "=v"(u[j]) : "v"(a), "v"(b));
                }
                asm("v_permlane32_swap_b32 %0, %1" : "+v"(u[0]), "+v"(u[2]));
                asm("v_permlane32_swap_b32 %0, %1" : "+v"(u[1]), "+v"(u[3]));
                asm("v_permlane32_swap_b32 %0, %1" : "+v"(u[4]), "+v"(u[6]));
                asm("v_permlane32_swap_b32 %0, %1" : "+v"(u[5]), "+v"(u[7]));
                union { unsigned int w4[4]; bfrag8 f; } c0, c1;
                c0.w4[0] = u[0]; c0.w4[1] = u[1]; c0.w4[2] = u[2]; c0.w4[3] = u[3];
                c1.w4[0] = u[4]; c1.w4[1] = u[5]; c1.w4[2] = u[6]; c1.w4[3] = u[7];

                acc[qh][0] = mfma_32x32x16(va[0][kh][0], c0.f, acc[qh][0]);
                acc[qh][0] = mfma_32x32x16(va[0][kh][1], c1.f, acc[qh][0]);
                acc[qh][1] = mfma_32x32x16(va[1][kh][0], c0.f, acc[qh][1]);
                acc[qh][1] = mfma_32x32x16(va[1][kh][1], c1.f, acc[qh][1]);
            }
        }

        // ---- F/G: own DMA half arrived; rendezvous -> slot kt+4 fully present
        asm volatile("s_waitcnt vmcnt(0)" ::: "memory");
        __builtin_amdgcn_s_barrier();
    }

    // ---- epilogue: tree-reduce the 4 kt-class partials per sub, then LN ----
    auto dump = [&](int region) {
        unsigned char* base = sm + region * 16384;
        #pragma unroll
        for (int qh = 0; qh < 2; ++qh)
            #pragma unroll
            for (int dh = 0; dh < 2; ++dh)
                #pragma unroll
                for (int jj = 0; jj < 4; ++jj) {
                    floatx4 t;
                    #pragma unroll
                    for (int e = 0; e < 4; ++e) t[e] = acc[qh][dh][jj * 4 + e];
                    *(floatx4*)(base + (qh * 2 + dh) * 4096 + jj * 1024 + lane * 16) = t;
                }
    };
    auto addin = [&](int region) {
        const unsigned char* base = sm + region * 16384;
        #pragma unroll
        for (int qh = 0; qh < 2; ++qh)
            #pragma unroll
            for (int dh = 0; dh < 2; ++dh)
                #pragma unroll
                for (int jj = 0; jj < 4; ++jj) {
                    floatx4 t = *(const floatx4*)(base + (qh * 2 + dh) * 4096 + jj * 1024 + lane * 16);
                    #pragma unroll
                    for (int e = 0; e < 4; ++e) acc[qh][dh][jj * 4 + e] += t[e];
                }
    };

    if (wq >= 2) dump(sub * 2 + (wq - 2));
    __syncthreads();
    if (wq <= 1) addin(sub * 2 + wq);        // wq0 += wq2 ; wq1 += wq3
    if (wq == 1) dump(sub * 2 + 1);          // in-wave read-then-write, dep-ordered
    __syncthreads();
    if (wq == 0) {
        addin(sub * 2 + 1);                  // += (wq1+wq3)  -> full sum
        #pragma unroll
        for (int qh = 0; qh < 2; ++qh) {
            float ss = 0.0f, ss2 = 0.0f;
            #pragma unroll
            for (int dh = 0; dh < 2; ++dh)
                #pragma unroll
                for (int r = 0; r < 16; ++r) { float x = acc[qh][dh][r]; ss += x; ss2 += x * x; }
            ss  += __shfl_xor(ss, 32);       // partner lane holds complementary d set
            ss2 += __shfl_xor(ss2, 32);
            float mean = ss * (1.0f / 64.0f);
            float var  = ss2 * (1.0f / 64.0f) - mean * mean;
            float rstd = rsqrtf(var + 1e-12f);
            float* orow = outp + (size_t)(bh * SEQ + qbase + qh * 32 + l32) * 64;
            #pragma unroll
            for (int dh = 0; dh < 2; ++dh)
                #pragma unroll
                for (int jj = 0; jj < 4; ++jj) {
                    const int d0 = dh * 32 + jj * 8 + 4 * hi;
                    floatx4 gg = *(const floatx4*)(gammap + d0);
                    floatx4 bb = *(const floatx4*)(betap + d0);
                    floatx4 o;
                    #pragma unroll
                    for (int e = 0; e < 4; ++e)
                        o[e] = (acc[qh][dh][jj * 4 + e] - mean) * rstd * gg[e] + bb[e];
                    *(floatx4*)(orow + d0) = o;
                }
        }
    }
}

// ================= fallback (round-2 kernel — proven) =================
#define KROW 72
#define SROW 40
__global__ __launch_bounds__(256, 4)
void normattn_fallback(const float* __restrict__ qp, const float* __restrict__ kp,
                       const float* __restrict__ vp, const int* __restrict__ maskp,
                       const float* __restrict__ gammap, const float* __restrict__ betap,
                       float* __restrict__ outp)
{
    __shared__ __attribute__((aligned(16))) __bf16 sQ[64 * KROW];
    __shared__ __attribute__((aligned(16))) __bf16 sK[64 * KROW];
    __shared__ __attribute__((aligned(16))) __bf16 sV[64 * KROW];
    __shared__ __attribute__((aligned(16))) __bf16 sS[4][16 * SROW];
    __shared__ __attribute__((aligned(8)))  unsigned int sMw[64][2];

    const int tid = threadIdx.x, wave = tid >> 6, lane = tid & 63;
    const int quad = lane >> 4, l16 = lane & 15;
    const int q0 = blockIdx.x * 64, bh = blockIdx.y;
    const int base = bh * SEQ * HD;
    {
        const floatx4* qg = (const floatx4*)(qp + base + q0 * HD);
        #pragma unroll
        for (int it = 0; it < 4; ++it) {
            int idx = tid + it * 256, r = idx >> 4, c = idx & 15;
            floatx4 val = qg[idx];
            bf16x4 pk = {(__bf16)val[0], (__bf16)val[1], (__bf16)val[2], (__bf16)val[3]};
            *(bf16x4*)&sQ[r * KROW + c * 4] = pk;
        }
    }
    __syncthreads();
    bfrag8 qa0 = *(const bfrag8*)&sQ[(wave * 16 + l16) * KROW + quad * 8];
    bfrag8 qa1 = *(const bfrag8*)&sQ[(wave * 16 + l16) * KROW + quad * 8 + 32];
    floatx4 acc[4];
    #pragma unroll
    for (int i = 0; i < 4; ++i) acc[i] = (floatx4)0.0f;
    const int qrow_loc = wave * 16 + quad * 4;
    const int qrb = q0 + qrow_loc;
    for (int kb = 0; kb < SEQ; kb += 64) {
        __syncthreads();
        {
            const floatx4* kg = (const floatx4*)(kp + base + kb * HD);
            #pragma unroll
            for (int it = 0; it < 4; ++it) {
                int idx = tid + it * 256, r = idx >> 4, c = idx & 15;
                floatx4 val = kg[idx];
                bf16x4 pk = {(__bf16)val[0], (__bf16)val[1], (__bf16)val[2], (__bf16)val[3]};
                *(bf16x4*)&sK[r * KROW + c * 4] = pk;
            }
        }
        {
            int d = tid & 63;
            #pragma unroll
            for (int it = 0; it < 4; ++it) {
                int k4 = (tid >> 6) + it * 4;
                bf16x4 pk;
                #pragma unroll
                for (int i = 0; i < 4; ++i) pk[i] = (__bf16)vp[base + (kb + k4 * 4 + i) * HD + d];
                *(bf16x4*)&sV[d * KROW + k4 * 4] = pk;
            }
        }
        #pragma unroll
        for (int it = 0; it < 16; ++it) {
            int rr = it * 4 + wave;
            unsigned long long bl = __ballot(maskp[(q0 + rr) * SEQ + kb + lane] != 0);
            if (lane == 0) { sMw[rr][0] = (unsigned)bl; sMw[rr][1] = (unsigned)(bl >> 32); }
        }
        __syncthreads();
        unsigned long long mrow[4];
        #pragma unroll
        for (int r = 0; r < 4; ++r) mrow[r] = *(const unsigned long long*)&sMw[qrow_loc + r][0];
        #pragma unroll
        for (int kc = 0; kc < 64; kc += 32) {
            floatx4 s0 = (floatx4)0.0f, s1 = (floatx4)0.0f;
            bfrag8 b00 = *(const bfrag8*)&sK[(kc + l16) * KROW + quad * 8];
            bfrag8 b01 = *(const bfrag8*)&sK[(kc + l16) * KROW + quad * 8 + 32];
            bfrag8 b10 = *(const bfrag8*)&sK[(kc + 16 + l16) * KROW + quad * 8];
            bfrag8 b11 = *(const bfrag8*)&sK[(kc + 16 + l16) * KROW + quad * 8 + 32];
            s0 = mfma_16x16x32(qa0, b00, s0);
            s0 = mfma_16x16x32(qa1, b01, s0);
            s1 = mfma_16x16x32(qa0, b10, s1);
            s1 = mfma_16x16x32(qa1, b11, s1);
            #pragma unroll
            for (int r = 0; r < 4; ++r) {
                float v0 = ((mrow[r] >> (kc + l16)) & 1ull) ? s0[r] : -10000.0f;
                float v1 = ((mrow[r] >> (kc + 16 + l16)) & 1ull) ? s1[r] : -10000.0f;
                sS[wave][(quad * 4 + r) * SROW + l16] = (__bf16)v0;
                sS[wave][(quad * 4 + r) * SROW + 16 + l16] = (__bf16)v1;
            }
            asm volatile("s_waitcnt lgkmcnt(0)" ::: "memory");
            bfrag8 pa = *(const bfrag8*)&sS[wave][l16 * SROW + quad * 8];
            #pragma unroll
            for (int nt = 0; nt < 4; ++nt) {
                bfrag8 vb = *(const bfrag8*)&sV[(nt * 16 + l16) * KROW + kc + quad * 8];
                acc[nt] = mfma_16x16x32(pa, vb, acc[nt]);
            }
        }
    }
    float g[4], bt[4];
    #pragma unroll
    for (int nt = 0; nt < 4; ++nt) { g[nt] = gammap[nt * 16 + l16]; bt[nt] = betap[nt * 16 + l16]; }
    #pragma unroll
    for (int r = 0; r < 4; ++r) {
        float s = 0.0f, s2 = 0.0f;
        #pragma unroll
        for (int nt = 0; nt < 4; ++nt) { float xx = acc[nt][r]; s += xx; s2 += xx * xx; }
        #pragma unroll
        for (int off = 1; off < 16; off <<= 1) { s += __shfl_xor(s, off); s2 += __shfl_xor(s2, off); }
        float mean = s * (1.0f / 64.0f);
        float var = s2 * (1.0f / 64.0f) - mean * mean;
        float rstd = rsqrtf(var + 1e-12f);
        float* orow = outp + base + (qrb + r) * HD;
        #pragma unroll
        for (int nt = 0; nt < 4; ++nt)
            orow[nt * 16 + l16] = (acc[nt][r] - mean) * rstd * g[nt] + bt[nt];
    }
}

extern "C" void kernel_launch(void* const* d_in, const int* in_sizes, int n_in,
                              void* d_out, int out_size, void* d_ws, size_t ws_size,
                              hipStream_t stream) {
    const float* q     = (const float*)d_in[0];
    const float* k     = (const float*)d_in[1];
    const float* v     = (const float*)d_in[2];
    const int*   mask  = (const int*)d_in[3];
    const float* gamma = (const float*)d_in[4];
    const float* beta  = (const float*)d_in[5];
    float* out = (float*)d_out;

    if (ws_size >= WS_NEED) {
        unsigned char* ws = (unsigned char*)d_ws;
        prep_kernel<<<3328, 256, 0, stream>>>(q, k, v, mask, ws);
        dim3 grid(16, NBH);
        normattn_main<<<grid, 512, 0, stream>>>(ws, gamma, beta, out);
    } else {
        dim3 grid(32, NBH);
        normattn_fallback<<<grid, 256, 0, stream>>>(q, k, v, mask, gamma, beta, out);
    }
}

// Round 7
// 135.329 us; speedup vs baseline: 1.4212x; 1.1426x over previous
//
#include <hip/hip_runtime.h>

#define SEQ 2048
#define HD 64
#define NBH 24

// ---------------- workspace layout (proven rounds 5-8; K/VT chunk-XOR-swizzled since r11) ----------------
#define MB_OFF   0
#define MB_BYTES (32 * 32 * 512)                 // 512 KB: [qtb][kt][64 q-rows][u64 of k-bits]
#define QB_OFF   (MB_OFF + MB_BYTES)
#define QK_BYTES (NBH * SEQ * HD * 2)            // 6 MB bf16, plain 128B rows
#define KB_OFF   (QB_OFF + QK_BYTES)
#define VT_OFF   (KB_OFF + QK_BYTES)             // V^T pre-tiled: [bh][kt] 8KB tiles, d-major 128B rows
#define WS_NEED  ((size_t)(VT_OFF + QK_BYTES))   // ~18.5 MB

typedef __bf16 bfrag8 __attribute__((ext_vector_type(8)));
typedef __bf16 bf16x4 __attribute__((ext_vector_type(4)));
typedef float  floatx4 __attribute__((ext_vector_type(4)));
typedef float  floatx16 __attribute__((ext_vector_type(16)));

__device__ __forceinline__ floatx4 mfma_16x16x32(bfrag8 a, bfrag8 b, floatx4 c) {
    return __builtin_amdgcn_mfma_f32_16x16x32_bf16(a, b, c, 0, 0, 0);
}
__device__ __forceinline__ floatx16 mfma_32x32x16(bfrag8 a, bfrag8 b, floatx16 c) {
    return __builtin_amdgcn_mfma_f32_32x32x16_bf16(a, b, c, 0, 0, 0);
}
__device__ __forceinline__ void gld16(const unsigned char* g, unsigned char* l) {
    __builtin_amdgcn_global_load_lds(
        (const __attribute__((address_space(1))) unsigned int*)g,
        (__attribute__((address_space(3))) unsigned int*)l, 16, 0, 0);
}

// ================= prepass (rounds 5-8 + chunk-XOR swizzle on K and V^T rows — proven r11) =================
__global__ __launch_bounds__(256)
void prep_kernel(const float* __restrict__ qp, const float* __restrict__ kp,
                 const float* __restrict__ vp, const int* __restrict__ maskp,
                 unsigned char* __restrict__ ws)
{
    __shared__ __attribute__((aligned(16))) unsigned char parena[64 * 68 * 4];
    const int t = threadIdx.x;
    const int b = blockIdx.x;

    if (b < 1536) {
        int gt  = b * 256 + t;
        int row = gt >> 3;
        int c   = gt & 7;
        const floatx4* qs = (const floatx4*)(qp + row * 64 + c * 8);
        const floatx4* ks = (const floatx4*)(kp + row * 64 + c * 8);
        floatx4 q0 = qs[0], q1 = qs[1];
        floatx4 k0 = ks[0], k1 = ks[1];
        bfrag8 qpk, kpk;
        #pragma unroll
        for (int i = 0; i < 4; ++i) {
            qpk[i] = (__bf16)q0[i]; qpk[4 + i] = (__bf16)q1[i];
            kpk[i] = (__bf16)k0[i]; kpk[4 + i] = (__bf16)k1[i];
        }
        *(bfrag8*)(ws + QB_OFF + row * 128 + c * 16) = qpk;                       // Q linear (read once)
        *(bfrag8*)(ws + KB_OFF + row * 128 + ((c ^ (row & 7)) * 16)) = kpk;       // K swizzled
    } else if (b < 2304) {
        int bb = b - 1536, bh = bb >> 5, kt = bb & 31;
        float* lf = (float*)parena;                 // [64 k][68 d]
        const floatx4* vg = (const floatx4*)(vp + (bh * SEQ + kt * 64) * 64);
        #pragma unroll
        for (int it = 0; it < 4; ++it) {
            int f = t + it * 256;
            int r = f >> 4, c4 = f & 15;
            floatx4 val = vg[f];
            #pragma unroll
            for (int i = 0; i < 4; ++i) lf[r * 68 + c4 * 4 + i] = val[i];
        }
        __syncthreads();
        int d = t >> 2, kseg = t & 3;
        unsigned char* tb = ws + VT_OFF + (size_t)(bh * 32 + kt) * 8192 + d * 128;
        #pragma unroll
        for (int jj = 0; jj < 2; ++jj) {
            bfrag8 pk;
            #pragma unroll
            for (int e = 0; e < 8; ++e)
                pk[e] = (__bf16)lf[(kseg * 16 + jj * 8 + e) * 68 + d];
            *(bfrag8*)(tb + (((kseg * 2 + jj) ^ (d & 7)) * 16)) = pk;             // V^T swizzled
        }
    } else {
        int cc = b - 2304, qtb = cc >> 5, kt = cc & 31;
        const int w = t >> 6, lane = t & 63;
        #pragma unroll
        for (int it = 0; it < 16; ++it) {
            int rr = it * 4 + w;
            unsigned long long bl = __ballot(maskp[(qtb * 64 + rr) * SEQ + kt * 64 + lane] != 0);
            if (lane == 0)
                *(unsigned long long*)(ws + MB_OFF + (size_t)((qtb * 32 + kt) * 64 + rr) * 8) = bl;
        }
    }
}

// ======== main (round 15): round-11/round-3 kernel byte-for-byte + XCD-aware block swizzle.
//          Flat grid 768; id -> (xcd = id&7, s = id>>3, bh = xcd*3 + s/32, qtb = s%32):
//          all 32 q-blocks of a bh land on one XCD -> K/V panel (1.5MB/3bh) L2-resident,
//          global_load_lds DMAs become L2 hits instead of Infinity-Cache misses. ========
__global__ __launch_bounds__(256, 2)
void normattn_main(const unsigned char* __restrict__ ws,
                   const float* __restrict__ gammap, const float* __restrict__ betap,
                   float* __restrict__ outp)
{
    __shared__ __attribute__((aligned(16))) unsigned char sm[65536];   // 4 x 16KB private slots

    const int tid  = threadIdx.x;
    const int w    = tid >> 6;
    const int lane = tid & 63;
    const int l32  = lane & 31;
    const int hi   = lane >> 5;

    // XCD-aware decode (T1): keep the 32 qtb-blocks of each bh on one XCD
    const int id   = blockIdx.x;
    const int xcd  = id & 7;
    const int s    = id >> 3;           // 0..95
    const int bh   = xcd * 3 + (s >> 5);
    const int qtb  = s & 31;
    const int q0   = qtb * 64;

    unsigned char* slotK = sm + w * 16384;
    unsigned char* slotV = slotK + 8192;

    const unsigned char* gKt = ws + KB_OFF + (size_t)(bh * SEQ) * 128;      // + kt*8192
    const unsigned char* gVt = ws + VT_OFF + (size_t)(bh * 32) * 8192;      // + kt*8192
    const unsigned char* gMb = ws + MB_OFF + (size_t)(qtb * 32) * 512;      // + kt*512

    // Q fragments, both q-halves (B-operand, 32x32x16): lane holds col q = qh*32+l32
    bfrag8 qb[2][4];
    #pragma unroll
    for (int qh = 0; qh < 2; ++qh)
        #pragma unroll
        for (int dstep = 0; dstep < 4; ++dstep)
            qb[qh][dstep] = *(const bfrag8*)(ws + QB_OFF +
                (size_t)(bh * SEQ + q0 + qh * 32 + l32) * 128 + dstep * 32 + hi * 16);

    // acc[qh][dh]: O^T[d = dh*32 + (r&3)+4*hi+8*(r>>2)][q = qh*32+l32], partial over kt = w (mod 4)
    floatx16 acc[2][2];
    #pragma unroll
    for (int i = 0; i < 4; ++i) acc[i >> 1][i & 1] = (floatx16)0.0f;

    auto stage = [&](int kt) {
        const unsigned char* gk = gKt + (size_t)kt * 8192 + lane * 16;
        const unsigned char* gv = gVt + (size_t)kt * 8192 + lane * 16;
        #pragma unroll
        for (int c = 0; c < 8; ++c) {
            gld16(gk + c * 1024, slotK + c * 1024);
            gld16(gv + c * 1024, slotV + c * 1024);
        }
    };
    unsigned long long mnx0, mnx1;
    auto loadmask = [&](int kt) {
        mnx0 = *(const unsigned long long*)(gMb + (size_t)kt * 512 + l32 * 8);
        mnx1 = *(const unsigned long long*)(gMb + (size_t)kt * 512 + 256 + l32 * 8);
    };

    stage(w);
    loadmask(w);

    for (int i = 0; i < 8; ++i) {
        const int kt = w + 4 * i;
        asm volatile("s_waitcnt vmcnt(0)" ::: "memory");     // tile kt + masks arrived
        const unsigned long long mr0 = mnx0, mr1 = mnx1;

        // all 16 fragment reads up front (frees slot for next DMA as early as possible)
        bfrag8 ka[2][4], va[2][2][2];
        #pragma unroll
        for (int kh = 0; kh < 2; ++kh)
            #pragma unroll
            for (int d = 0; d < 4; ++d)
                ka[kh][d] = *(const bfrag8*)(slotK + (kh * 32 + l32) * 128 +
                                             (((d * 2 + hi) ^ (l32 & 7)) << 4));
        #pragma unroll
        for (int dh = 0; dh < 2; ++dh)
            #pragma unroll
            for (int kh = 0; kh < 2; ++kh)
                #pragma unroll
                for (int ks = 0; ks < 2; ++ks)
                    va[dh][kh][ks] = *(const bfrag8*)(slotV + (dh * 32 + l32) * 128 +
                                                      (((kh * 4 + ks * 2 + hi) ^ (l32 & 7)) << 4));
        asm volatile("s_waitcnt lgkmcnt(0)" ::: "memory");   // slot free
        if (i < 7) { stage(kt + 4); loadmask(kt + 4); }      // DMA hides under compute below

        #pragma unroll
        for (int kh = 0; kh < 2; ++kh) {
            // QK^T (swapped): two independent 4-MFMA chains (qh=0,1)
            floatx16 st0 = (floatx16)0.0f, st1 = (floatx16)0.0f;
            #pragma unroll
            for (int d = 0; d < 4; ++d) {
                st0 = mfma_32x32x16(ka[kh][d], qb[0][d], st0);
                st1 = mfma_32x32x16(ka[kh][d], qb[1][d], st1);
            }
            #pragma unroll
            for (int qh = 0; qh < 2; ++qh) {
                const floatx16 st = qh ? st1 : st0;
                const unsigned long long mrow = qh ? mr1 : mr0;
                const unsigned bits = (unsigned)(mrow >> (kh * 32 + 4 * hi));
                unsigned u[8];
                #pragma unroll
                for (int j = 0; j < 8; ++j) {
                    const int kl0 = 2 * (j & 1) + 8 * (j >> 1);
                    float a = ((bits >> kl0) & 1u) ? st[2 * j] : -10000.0f;
                    float b = ((bits >> (kl0 + 1)) & 1u) ? st[2 * j + 1] : -10000.0f;
                    asm("v_cvt_pk_bf16_f32 %0, %1, %2" : "=v"(u[j]) : "v"(a), "v"(b));
                }
                asm("v_permlane32_swap_b32 %0, %1" : "+v"(u[0]), "+v"(u[2]));
                asm("v_permlane32_swap_b32 %0, %1" : "+v"(u[1]), "+v"(u[3]));
                asm("v_permlane32_swap_b32 %0, %1" : "+v"(u[4]), "+v"(u[6]));
                asm("v_permlane32_swap_b32 %0, %1" : "+v"(u[5]), "+v"(u[7]));
                union { unsigned int w4[4]; bfrag8 f; } c0, c1;
                c0.w4[0] = u[0]; c0.w4[1] = u[1]; c0.w4[2] = u[2]; c0.w4[3] = u[3];
                c1.w4[0] = u[4]; c1.w4[1] = u[5]; c1.w4[2] = u[6]; c1.w4[3] = u[7];

                acc[qh][0] = mfma_32x32x16(va[0][kh][0], c0.f, acc[qh][0]);
                acc[qh][0] = mfma_32x32x16(va[0][kh][1], c1.f, acc[qh][0]);
                acc[qh][1] = mfma_32x32x16(va[1][kh][0], c0.f, acc[qh][1]);
                acc[qh][1] = mfma_32x32x16(va[1][kh][1], c1.f, acc[qh][1]);
            }
        }
    }

    // ---- epilogue: all waves dump partials (conflict-free layout), 2 waves reduce + LN ----
    #pragma unroll
    for (int qh = 0; qh < 2; ++qh)
        #pragma unroll
        for (int dh = 0; dh < 2; ++dh)
            #pragma unroll
            for (int jj = 0; jj < 4; ++jj) {
                floatx4 t;
                #pragma unroll
                for (int e = 0; e < 4; ++e) t[e] = acc[qh][dh][jj * 4 + e];
                *(floatx4*)(sm + w * 16384 + (qh * 2 + dh) * 4096 + jj * 1024 + lane * 16) = t;
            }
    __syncthreads();
    if (w < 2) {
        const int qh = w;
        floatx16 o2[2];
        #pragma unroll
        for (int dh = 0; dh < 2; ++dh)
            #pragma unroll
            for (int jj = 0; jj < 4; ++jj) {
                floatx4 s4 = (floatx4)0.0f;
                #pragma unroll
                for (int ww = 0; ww < 4; ++ww) {
                    floatx4 t = *(const floatx4*)(sm + ww * 16384 + (qh * 2 + dh) * 4096 +
                                                  jj * 1024 + lane * 16);
                    #pragma unroll
                    for (int e = 0; e < 4; ++e) s4[e] += t[e];
                }
                #pragma unroll
                for (int e = 0; e < 4; ++e) o2[dh][jj * 4 + e] = s4[e];
            }
        float ss = 0.0f, ss2 = 0.0f;
        #pragma unroll
        for (int dh = 0; dh < 2; ++dh)
            #pragma unroll
            for (int r = 0; r < 16; ++r) { float x = o2[dh][r]; ss += x; ss2 += x * x; }
        ss  += __shfl_xor(ss, 32);                   // partner lane holds complementary d set
        ss2 += __shfl_xor(ss2, 32);
        float mean = ss * (1.0f / 64.0f);
        float var  = ss2 * (1.0f / 64.0f) - mean * mean;
        float rstd = rsqrtf(var + 1e-12f);
        float* orow = outp + (size_t)(bh * SEQ + q0 + qh * 32 + l32) * 64;
        #pragma unroll
        for (int dh = 0; dh < 2; ++dh)
            #pragma unroll
            for (int jj = 0; jj < 4; ++jj) {
                const int d0 = dh * 32 + jj * 8 + 4 * hi;
                floatx4 gg = *(const floatx4*)(gammap + d0);
                floatx4 bb = *(const floatx4*)(betap + d0);
                floatx4 o;
                #pragma unroll
                for (int e = 0; e < 4; ++e)
                    o[e] = (o2[dh][jj * 4 + e] - mean) * rstd * gg[e] + bb[e];
                *(floatx4*)(orow + d0) = o;
            }
    }
}

// ================= fallback (round-2 kernel — proven) =================
#define KROW 72
#define SROW 40
__global__ __launch_bounds__(256, 4)
void normattn_fallback(const float* __restrict__ qp, const float* __restrict__ kp,
                       const float* __restrict__ vp, const int* __restrict__ maskp,
                       const float* __restrict__ gammap, const float* __restrict__ betap,
                       float* __restrict__ outp)
{
    __shared__ __attribute__((aligned(16))) __bf16 sQ[64 * KROW];
    __shared__ __attribute__((aligned(16))) __bf16 sK[64 * KROW];
    __shared__ __attribute__((aligned(16))) __bf16 sV[64 * KROW];
    __shared__ __attribute__((aligned(16))) __bf16 sS[4][16 * SROW];
    __shared__ __attribute__((aligned(8)))  unsigned int sMw[64][2];

    const int tid = threadIdx.x, wave = tid >> 6, lane = tid & 63;
    const int quad = lane >> 4, l16 = lane & 15;
    const int q0 = blockIdx.x * 64, bh = blockIdx.y;
    const int base = bh * SEQ * HD;
    {
        const floatx4* qg = (const floatx4*)(qp + base + q0 * HD);
        #pragma unroll
        for (int it = 0; it < 4; ++it) {
            int idx = tid + it * 256, r = idx >> 4, c = idx & 15;
            floatx4 val = qg[idx];
            bf16x4 pk = {(__bf16)val[0], (__bf16)val[1], (__bf16)val[2], (__bf16)val[3]};
            *(bf16x4*)&sQ[r * KROW + c * 4] = pk;
        }
    }
    __syncthreads();
    bfrag8 qa0 = *(const bfrag8*)&sQ[(wave * 16 + l16) * KROW + quad * 8];
    bfrag8 qa1 = *(const bfrag8*)&sQ[(wave * 16 + l16) * KROW + quad * 8 + 32];
    floatx4 acc[4];
    #pragma unroll
    for (int i = 0; i < 4; ++i) acc[i] = (floatx4)0.0f;
    const int qrow_loc = wave * 16 + quad * 4;
    const int qrb = q0 + qrow_loc;
    for (int kb = 0; kb < SEQ; kb += 64) {
        __syncthreads();
        {
            const floatx4* kg = (const floatx4*)(kp + base + kb * HD);
            #pragma unroll
            for (int it = 0; it < 4; ++it) {
                int idx = tid + it * 256, r = idx >> 4, c = idx & 15;
                floatx4 val = kg[idx];
                bf16x4 pk = {(__bf16)val[0], (__bf16)val[1], (__bf16)val[2], (__bf16)val[3]};
                *(bf16x4*)&sK[r * KROW + c * 4] = pk;
            }
        }
        {
            int d = tid & 63;
            #pragma unroll
            for (int it = 0; it < 4; ++it) {
                int k4 = (tid >> 6) + it * 4;
                bf16x4 pk;
                #pragma unroll
                for (int i = 0; i < 4; ++i) pk[i] = (__bf16)vp[base + (kb + k4 * 4 + i) * HD + d];
                *(bf16x4*)&sV[d * KROW + k4 * 4] = pk;
            }
        }
        #pragma unroll
        for (int it = 0; it < 16; ++it) {
            int rr = it * 4 + wave;
            unsigned long long bl = __ballot(maskp[(q0 + rr) * SEQ + kb + lane] != 0);
            if (lane == 0) { sMw[rr][0] = (unsigned)bl; sMw[rr][1] = (unsigned)(bl >> 32); }
        }
        __syncthreads();
        unsigned long long mrow[4];
        #pragma unroll
        for (int r = 0; r < 4; ++r) mrow[r] = *(const unsigned long long*)&sMw[qrow_loc + r][0];
        #pragma unroll
        for (int kc = 0; kc < 64; kc += 32) {
            floatx4 s0 = (floatx4)0.0f, s1 = (floatx4)0.0f;
            bfrag8 b00 = *(const bfrag8*)&sK[(kc + l16) * KROW + quad * 8];
            bfrag8 b01 = *(const bfrag8*)&sK[(kc + l16) * KROW + quad * 8 + 32];
            bfrag8 b10 = *(const bfrag8*)&sK[(kc + 16 + l16) * KROW + quad * 8];
            bfrag8 b11 = *(const bfrag8*)&sK[(kc + 16 + l16) * KROW + quad * 8 + 32];
            s0 = mfma_16x16x32(qa0, b00, s0);
            s0 = mfma_16x16x32(qa1, b01, s0);
            s1 = mfma_16x16x32(qa0, b10, s1);
            s1 = mfma_16x16x32(qa1, b11, s1);
            #pragma unroll
            for (int r = 0; r < 4; ++r) {
                float v0 = ((mrow[r] >> (kc + l16)) & 1ull) ? s0[r] : -10000.0f;
                float v1 = ((mrow[r] >> (kc + 16 + l16)) & 1ull) ? s1[r] : -10000.0f;
                sS[wave][(quad * 4 + r) * SROW + l16] = (__bf16)v0;
                sS[wave][(quad * 4 + r) * SROW + 16 + l16] = (__bf16)v1;
            }
            asm volatile("s_waitcnt lgkmcnt(0)" ::: "memory");
            bfrag8 pa = *(const bfrag8*)&sS[wave][l16 * SROW + quad * 8];
            #pragma unroll
            for (int nt = 0; nt < 4; ++nt) {
                bfrag8 vb = *(const bfrag8*)&sV[(nt * 16 + l16) * KROW + kc + quad * 8];
                acc[nt] = mfma_16x16x32(pa, vb, acc[nt]);
            }
        }
    }
    float g[4], bt[4];
    #pragma unroll
    for (int nt = 0; nt < 4; ++nt) { g[nt] = gammap[nt * 16 + l16]; bt[nt] = betap[nt * 16 + l16]; }
    #pragma unroll
    for (int r = 0; r < 4; ++r) {
        float s = 0.0f, s2 = 0.0f;
        #pragma unroll
        for (int nt = 0; nt < 4; ++nt) { float xx = acc[nt][r]; s += xx; s2 += xx * xx; }
        #pragma unroll
        for (int off = 1; off < 16; off <<= 1) { s += __shfl_xor(s, off); s2 += __shfl_xor(s2, off); }
        float mean = s * (1.0f / 64.0f);
        float var = s2 * (1.0f / 64.0f) - mean * mean;
        float rstd = rsqrtf(var + 1e-12f);
        float* orow = outp + base + (qrb + r) * HD;
        #pragma unroll
        for (int nt = 0; nt < 4; ++nt)
            orow[nt * 16 + l16] = (acc[nt][r] - mean) * rstd * g[nt] + bt[nt];
    }
}

extern "C" void kernel_launch(void* const* d_in, const int* in_sizes, int n_in,
                              void* d_out, int out_size, void* d_ws, size_t ws_size,
                              hipStream_t stream) {
    const float* q     = (const float*)d_in[0];
    const float* k     = (const float*)d_in[1];
    const float* v     = (const float*)d_in[2];
    const int*   mask  = (const int*)d_in[3];
    const float* gamma = (const float*)d_in[4];
    const float* beta  = (const float*)d_in[5];
    float* out = (float*)d_out;

    if (ws_size >= WS_NEED) {
        unsigned char* ws = (unsigned char*)d_ws;
        prep_kernel<<<3328, 256, 0, stream>>>(q, k, v, mask, ws);
        normattn_main<<<768, 256, 0, stream>>>(ws, gamma, beta, out);
    } else {
        dim3 grid(32, NBH);
        normattn_fallback<<<grid, 256, 0, stream>>>(q, k, v, mask, gamma, beta, out);
    }
}